// Round 2
// baseline (451.853 us; speedup 1.0000x reference)
//
#include <hip/hip_runtime.h>
#include <math.h>

// Causal depthwise conv (K=4) + SiLU. B=4, S=8192, H=2048, fp32.
#define CB 4
#define CS 8192
#define CH 2048
#define CH4 (CH / 4)      // 512 float4 lanes per (b,t) row
#define TT 32             // timesteps per thread (halo 3/32 ~ 9% extra read)
#define PF 8              // prefetch depth: 8 global_load_dwordx4 in flight

__device__ __forceinline__ float silu(float v) {
    // v * sigmoid(v) with raw v_rcp_f32 (~1 ULP; threshold is 2.16e-1)
    float e = __expf(-v);
    return v * __builtin_amdgcn_rcpf(1.0f + e);
}

__global__ __launch_bounds__(256) void dwconv_silu_kernel(
        const float* __restrict__ x,
        const float* __restrict__ w,
        float* __restrict__ y) {
    const int tid = blockIdx.x * 256 + threadIdx.x;
    const int h4 = tid & (CH4 - 1);          // consecutive lanes -> contiguous 1KB/wave
    const int strip = tid >> 9;              // tid / 512
    const int b = strip >> 8;                // strips per batch = S/TT = 256
    const int t0 = (strip & 255) * TT;

    const float4* __restrict__ xb = reinterpret_cast<const float4*>(x) + (size_t)b * CS * CH4 + h4;
    float4* __restrict__ yb = reinterpret_cast<float4*>(y) + (size_t)b * CS * CH4 + h4;

    // Weight rows for channels h = 4*h4 .. 4*h4+3 (L2-resident, 64B/thread once)
    const float4* __restrict__ wv = reinterpret_cast<const float4*>(w) + (size_t)h4 * 4;
    const float4 wr0 = wv[0];
    const float4 wr1 = wv[1];
    const float4 wr2 = wv[2];
    const float4 wr3 = wv[3];

    const float4 z = make_float4(0.f, 0.f, 0.f, 0.f);
    // Sliding causal window: x[t-3], x[t-2], x[t-1] (zero-padded at t<0).
    float4 xm3 = (t0 >= 3) ? xb[(size_t)(t0 - 3) * CH4] : z;
    float4 xm2 = (t0 >= 2) ? xb[(size_t)(t0 - 2) * CH4] : z;
    float4 xm1 = (t0 >= 1) ? xb[(size_t)(t0 - 1) * CH4] : z;

    // Software pipeline: keep PF independent loads in flight at all times.
    float4 buf[PF];
    #pragma unroll
    for (int i = 0; i < PF; ++i) buf[i] = xb[(size_t)(t0 + i) * CH4];

    #pragma unroll
    for (int tt = 0; tt < TT; tt += PF) {
        #pragma unroll
        for (int j = 0; j < PF; ++j) {
            const int t = t0 + tt + j;
            const float4 cur = buf[j];
            // Issue the replacement load immediately (independent of compute).
            // Guard is compile-time uniform: last PF-group has nothing to fetch.
            if (tt + PF < TT) buf[j] = xb[(size_t)(t + PF) * CH4];

            float4 o;
            o.x = wr0.x * xm3.x + wr0.y * xm2.x + wr0.z * xm1.x + wr0.w * cur.x;
            o.y = wr1.x * xm3.y + wr1.y * xm2.y + wr1.z * xm1.y + wr1.w * cur.y;
            o.z = wr2.x * xm3.z + wr2.y * xm2.z + wr2.z * xm1.z + wr2.w * cur.z;
            o.w = wr3.x * xm3.w + wr3.y * xm2.w + wr3.z * xm1.w + wr3.w * cur.w;

            o.x = silu(o.x);
            o.y = silu(o.y);
            o.z = silu(o.z);
            o.w = silu(o.w);

            yb[(size_t)t * CH4] = o;

            xm3 = xm2;
            xm2 = xm1;
            xm1 = cur;
        }
    }
}

extern "C" void kernel_launch(void* const* d_in, const int* in_sizes, int n_in,
                              void* d_out, int out_size, void* d_ws, size_t ws_size,
                              hipStream_t stream) {
    const float* x = (const float*)d_in[0];   // (B, S, H) fp32
    const float* w = (const float*)d_in[1];   // (H, K) fp32
    float* y = (float*)d_out;                 // (B, S, H) fp32

    const int total_threads = CB * (CS / TT) * CH4;  // 4 * 256 * 512 = 524288
    dwconv_silu_kernel<<<total_threads / 256, 256, 0, stream>>>(x, w, y);
}